// Round 7
// baseline (538.360 us; speedup 1.0000x reference)
//
#include <hip/hip_runtime.h>

#define ROWS 2048
#define FLATK 33280
#define SUBK 2080
#define NSTEP 65
#define S_DIM 520
#define SPLITP 16
#define OUT_THETA 40960
#define OUT_MU 303104
#define LOSCALE 2048.0f
#define INV_LOSCALE (1.0f/2048.0f)

typedef __attribute__((ext_vector_type(8))) _Float16 f16x8;
typedef __attribute__((ext_vector_type(8))) unsigned short u16x8;
typedef __attribute__((ext_vector_type(4))) float f32x4;

union H16 { _Float16 h; unsigned short u; };

static __device__ __forceinline__ void split16(float v, unsigned short& hi, unsigned short& lo) {
    H16 a, b;
    a.h = (_Float16)v;
    float r = (v - (float)a.h) * LOSCALE;
    b.h = (_Float16)r;
    hi = a.u; lo = b.u;
}

// async global->LDS, 16B per lane; lds base must be wave-uniform
static __device__ __forceinline__ void glds16(const unsigned short* g, unsigned short* l) {
    __builtin_amdgcn_global_load_lds((const __attribute__((address_space(1))) unsigned int*)g,
                                     (__attribute__((address_space(3))) unsigned int*)l,
                                     16, 0, 0);
}

// ---------------- K0: pl1_w fp32 -> f16 hi/lo planes ----------------
__global__ __launch_bounds__(256) void k_cvtB(const float4* __restrict__ in,
                                              ushort4* __restrict__ outh,
                                              ushort4* __restrict__ outl, int n4) {
    int i = blockIdx.x * 256 + threadIdx.x;
    if (i >= n4) return;
    float4 v = in[i];
    unsigned short h0, h1, h2, h3, l0, l1, l2, l3;
    split16(v.x, h0, l0); split16(v.y, h1, l1);
    split16(v.z, h2, l2); split16(v.w, h3, l3);
    outh[i] = make_ushort4(h0, h1, h2, h3);
    outl[i] = make_ushort4(l0, l1, l2, l3);
}

// ---------------- K0b: w2 fp32 -> pre-packed per-lane MFMA fragments hi/lo ----------------
// slot s in [0,512): ot'=s>>7 (4 tiles of 16 channels), ks=(s>>6)&1, lane=s&63.
// Channel c = ot'*16 + (lane&15); k = ks*32 + (lane>>4)*8 + j.  (Same bytes as before:
// old z,ot enumeration == ot' = z*2+ot.)
__global__ __launch_bounds__(256) void k_cvtW(const float* __restrict__ w2,
                                              unsigned short* __restrict__ Wq) {
    int t = threadIdx.x;
    for (int s = t; s < 512; s += 256) {
        int otp = s >> 7, ks = (s >> 6) & 1, lane = s & 63;
        int m = lane & 15, kg = lane >> 4;
        const float* wp = w2 + (size_t)(otp * 16 + m) * 64 + ks * 32 + kg * 8;
#pragma unroll
        for (int j = 0; j < 8; j++) {
            unsigned short hh, ll;
            split16(wp[j], hh, ll);
            Wq[s * 8 + j] = hh;
            Wq[4096 + s * 8 + j] = ll;
        }
    }
}

// ---------------- K1: conv1 (VALU, ONCE) + conv2 (MFMA, all 64 channels) ----------------
// R7 restructure: z splits by ROWS (bl in [z*1024,(z+1)*1024)), not by channels.
// conv1 + x-stage now run ONCE per (bl,window) total (was duplicated across z = ~70us
// of redundant work). conv2 covers all 4 ot-tiles. A-planes store full FLATK rows for
// 1024 local rows -> same 68 MB footprint.
__global__ __launch_bounds__(256) void k_conv(const float* __restrict__ x,
                                              const float* __restrict__ w1, const float* __restrict__ b1,
                                              const unsigned short* __restrict__ Wq,
                                              const float* __restrict__ b2,
                                              unsigned short* __restrict__ Ah, unsigned short* __restrict__ Al,
                                              int z) {
    __shared__ __align__(16) float xs[8 * 64];                //  2 KB
    __shared__ __align__(16) float w1s[512];                  //  2 KB
    __shared__ float b1s[64];                                 // 256 B
    __shared__ __align__(16) unsigned short h1h[64 * 64];     //  8 KB
    __shared__ __align__(16) unsigned short h1l[64 * 64];     //  8 KB

    int t = threadIdx.x;
    int bll = blockIdx.x, st = blockIdx.y;     // bll = local row 0..1023
    int bl = z * 1024 + bll;                   // global (b,l) row
    int pbase = st * 64;
    int lane = t & 63, w = t >> 6;
    int m = lane & 15, kg = lane >> 4;

    // stage x window (zero-padded), w1, b1
    const float* xb = x + (size_t)bl * (8 * S_DIM);
    for (int i = t; i < 512; i += 256) {
        int ci = i >> 6, p = i & 63;
        int g = pbase + p;
        xs[i] = (g < S_DIM) ? xb[ci * S_DIM + g] : 0.f;
        w1s[i] = w1[i];
    }
    if (t < 64) b1s[t] = b1[t];

    // w2 B-fragments for ALL 4 ot-tiles (pre-packed by k_cvtW; coalesced 16B loads)
    f16x8 wh[4][2], wl[4][2];
    float b2v[4];
#pragma unroll
    for (int ot = 0; ot < 4; ot++) {
        b2v[ot] = b2[ot * 16 + m];
#pragma unroll
        for (int ks = 0; ks < 2; ks++) {
            int slot = (ot * 2 + ks) * 64 + lane;
            wh[ot][ks] = *(const f16x8*)&Wq[slot * 8];
            wl[ot][ks] = *(const f16x8*)&Wq[4096 + slot * 8];
        }
    }
    __syncthreads();

    // conv1: wave w -> channels [16w, 16w+16), pos = lane (runs ONCE per window now)
    {
        int pos = lane;
        int cg0 = w * 16;
        float xv[8];
#pragma unroll
        for (int ci = 0; ci < 8; ci++) xv[ci] = xs[ci * 64 + pos];
#pragma unroll
        for (int half = 0; half < 2; half++) {
            u16x8 ph, pl;
#pragma unroll
            for (int j = 0; j < 8; j++) {
                int c = cg0 + half * 8 + j;
                const float4 wa = *(const float4*)&w1s[c * 8];
                const float4 wb = *(const float4*)&w1s[c * 8 + 4];
                float a = b1s[c]
                    + wa.x * xv[0] + wa.y * xv[1] + wa.z * xv[2] + wa.w * xv[3]
                    + wb.x * xv[4] + wb.y * xv[5] + wb.z * xv[6] + wb.w * xv[7];
                a = fmaxf(a, 0.f);
                unsigned short hh, ll;
                split16(a, hh, ll);
                ph[j] = hh; pl[j] = ll;
            }
            int g = (cg0 >> 3) + half;
            int off = pos * 64 + ((g ^ (pos & 7)) << 3);
            *(u16x8*)&h1h[off] = ph;
            *(u16x8*)&h1l[off] = pl;
        }
    }
    __syncthreads();

    // conv2 MFMA: wave w -> pos tile [w*16, w*16+16), all 64 outs (4 ot-tiles)
    int p0 = w * 16;
    int prow = p0 + m;
    f16x8 a_h[2], a_l[2];
#pragma unroll
    for (int ks = 0; ks < 2; ks++) {
        int g = ks * 4 + kg;
        int off = prow * 64 + ((g ^ (prow & 7)) << 3);
        a_h[ks] = *(const f16x8*)&h1h[off];
        a_l[ks] = *(const f16x8*)&h1l[off];
    }

    size_t Abase = (size_t)bll * FLATK;
    int pos4 = pbase + p0 + kg * 4;          // 4 consecutive positions per lane
    bool ok = pos4 < (S_DIM - 3);
#pragma unroll
    for (int ot = 0; ot < 4; ot++) {
        f32x4 ah = {0.f, 0.f, 0.f, 0.f}, am = {0.f, 0.f, 0.f, 0.f};
#pragma unroll
        for (int ks = 0; ks < 2; ks++) {
            ah = __builtin_amdgcn_mfma_f32_16x16x32_f16(a_h[ks], wh[ot][ks], ah, 0, 0, 0);
            am = __builtin_amdgcn_mfma_f32_16x16x32_f16(a_l[ks], wh[ot][ks], am, 0, 0, 0);
            am = __builtin_amdgcn_mfma_f32_16x16x32_f16(a_h[ks], wl[ot][ks], am, 0, 0, 0);
        }
        if (ok) {
            unsigned short hh[4], ll[4];
#pragma unroll
            for (int r = 0; r < 4; r++) {
                float v = fmaxf(b2v[ot] + ah[r] + am[r] * INV_LOSCALE, 0.f);
                split16(v, hh[r], ll[r]);
            }
            size_t off2 = Abase + (size_t)(ot * 16 + m) * S_DIM + pos4;
            *reinterpret_cast<ushort4*>(&Ah[off2]) = make_ushort4(hh[0], hh[1], hh[2], hh[3]);
            *reinterpret_cast<ushort4*>(&Al[off2]) = make_ushort4(ll[0], ll[1], ll[2], ll[3]);
        }
    }
}

// ---------------- K2: MFMA GEMM, 64x256 tile over the z row-half, full-K slices ----------------
// flat grid 256 blocks (16 rt x 16 sk), 512 thr (8 waves). rt tiles the 1024 local rows;
// sk slices full FLATK (SUBK=2080, NSTEP=65). Inner loop identical to R6 (2-phase dbuf,
// granule swizzle). P sliced by sk; row = z*1024 + rr (k_head unchanged).
__global__ __launch_bounds__(512) void k_gemm(const unsigned short* __restrict__ Ah,
                                              const unsigned short* __restrict__ Al,
                                              const unsigned short* __restrict__ Bh,
                                              const unsigned short* __restrict__ Bl,
                                              float* __restrict__ P, int z) {
    __shared__ __align__(16) unsigned short As_h[2][64 * 32];    // 2 x 4 KB
    __shared__ __align__(16) unsigned short As_l[2][64 * 32];    // 2 x 4 KB
    __shared__ __align__(16) unsigned short Bs_h[2][256 * 32];   // 2 x 16 KB
    __shared__ __align__(16) unsigned short Bs_l[2][256 * 32];   // 2 x 16 KB

    int t = threadIdx.x;
    int bid = blockIdx.x;
    int sk = bid & 15, rt = bid >> 4;
    int row0 = rt * 64;                       // local row within the z half
    int kb0 = sk * SUBK;

    int w = t >> 6, lane = t & 63;
    int srow = lane >> 2;                                   // 0..15
    int sg = ((lane & 3) ^ ((lane >> 3) & 3)) * 8;          // swizzled source granule

    // staging assignment (5 glds16/wave/iter):
    //  waves 0-3: A-hi rows; waves 4-7: A-lo rows; every wave: 2x B-hi + 2x B-lo rows
    const unsigned short* gA = (w < 4 ? Ah : Al)
        + (size_t)(row0 + (w & 3) * 16 + srow) * FLATK + kb0 + sg;
    const unsigned short* gBh0 = Bh + (size_t)(w * 32 + srow) * FLATK + kb0 + sg;
    const unsigned short* gBl0 = Bl + (size_t)(w * 32 + srow) * FLATK + kb0 + sg;
    const size_t strideB16 = (size_t)16 * FLATK;
    int aoff = ((w & 3) * 16) * 32;
    int boff0 = (w * 32) * 32;
    int boff1 = (w * 32 + 16) * 32;

    int m = lane & 15, kg = lane >> 4;
    int kgs = (kg ^ ((m >> 1) & 3)) * 8;                    // swizzled read granule

    f32x4 acc_h[4][2], acc_m[4][2];
#pragma unroll
    for (int i = 0; i < 4; i++)
#pragma unroll
        for (int j = 0; j < 2; j++) {
            acc_h[i][j] = (f32x4){0.f, 0.f, 0.f, 0.f};
            acc_m[i][j] = (f32x4){0.f, 0.f, 0.f, 0.f};
        }

#define STAGE(c) do {                                         \
        if (w < 4) glds16(gA, &As_h[c][aoff]);                \
        else       glds16(gA, &As_l[c][aoff]);                \
        glds16(gBh0, &Bs_h[c][boff0]);                        \
        glds16(gBh0 + strideB16, &Bs_h[c][boff1]);            \
        glds16(gBl0, &Bs_l[c][boff0]);                        \
        glds16(gBl0 + strideB16, &Bs_l[c][boff1]);            \
        gA += 32; gBh0 += 32; gBl0 += 32;                     \
    } while (0)

#define COMPUTE(c) do {                                                                   \
        f16x8 a_h[4], a_l[4], b_h[2], b_l[2];                                             \
        _Pragma("unroll")                                                                 \
        for (int i = 0; i < 4; i++) {                                                     \
            int off = (i * 16 + m) * 32 + kgs;                                            \
            a_h[i] = *reinterpret_cast<const f16x8*>(&As_h[c][off]);                      \
            a_l[i] = *reinterpret_cast<const f16x8*>(&As_l[c][off]);                      \
        }                                                                                 \
        _Pragma("unroll")                                                                 \
        for (int j = 0; j < 2; j++) {                                                     \
            int off = (w * 32 + j * 16 + m) * 32 + kgs;                                   \
            b_h[j] = *reinterpret_cast<const f16x8*>(&Bs_h[c][off]);                      \
            b_l[j] = *reinterpret_cast<const f16x8*>(&Bs_l[c][off]);                      \
        }                                                                                 \
        _Pragma("unroll")                                                                 \
        for (int i = 0; i < 4; i++)                                                       \
            _Pragma("unroll")                                                             \
            for (int j = 0; j < 2; j++) {                                                 \
                acc_h[i][j] = __builtin_amdgcn_mfma_f32_16x16x32_f16(a_h[i], b_h[j], acc_h[i][j], 0, 0, 0); \
                acc_m[i][j] = __builtin_amdgcn_mfma_f32_16x16x32_f16(a_l[i], b_h[j], acc_m[i][j], 0, 0, 0); \
                acc_m[i][j] = __builtin_amdgcn_mfma_f32_16x16x32_f16(a_h[i], b_l[j], acc_m[i][j], 0, 0, 0); \
            }                                                                             \
    } while (0)

    // prologue: stage k-block 0 into buf0
    STAGE(0);
    __syncthreads();   // drains vmcnt -> buf0 visible

    int cur = 0;
    for (int it = 0; it < NSTEP - 1; ++it) {
        STAGE(cur ^ 1);    // issue next k-block loads (in flight during compute)
        COMPUTE(cur);
        __syncthreads();   // drains vmcnt (stage done) + lgkm (reads done), syncs
        cur ^= 1;
    }
    COMPUTE(cur);          // last k-block

#undef STAGE
#undef COMPUTE

    float* Pp = P + (size_t)sk * (ROWS * 256);
    int rbase = z * 1024 + row0 + kg * 4;
    int cbase = w * 32 + m;
#pragma unroll
    for (int i = 0; i < 4; i++)
#pragma unroll
        for (int j = 0; j < 2; j++)
#pragma unroll
            for (int r = 0; r < 4; r++) {
                int rr = rbase + i * 16 + r;
                int cc = cbase + j * 16;
                Pp[(size_t)rr * 256 + cc] = acc_h[i][j][r] + acc_m[i][j][r] * INV_LOSCALE;
            }
}

// ---------------- K3: reduce + bias + relu + pl2 + Theta ----------------
__global__ __launch_bounds__(128) void k_head(const float* __restrict__ P,
                                              const float* __restrict__ pl1b,
                                              const float* __restrict__ pl2w,
                                              const float* __restrict__ pl2b,
                                              float* __restrict__ out) {
    __shared__ __align__(16) float hs[256];
    __shared__ float Rls[128];
    int row = blockIdx.x;
    int t = threadIdx.x;
    for (int c = t; c < 256; c += 128) {
        float v = pl1b[c];
#pragma unroll
        for (int zz = 0; zz < SPLITP; zz++) v += P[(size_t)zz * (ROWS * 256) + (size_t)row * 256 + c];
        hs[c] = fmaxf(v, 0.f);
    }
    __syncthreads();
    {
        float v = pl2b[t];
        const float4* wr = reinterpret_cast<const float4*>(pl2w + (size_t)t * 256);
        const float4* hv = reinterpret_cast<const float4*>(hs);
#pragma unroll 8
        for (int c4 = 0; c4 < 64; c4++) {
            float4 wq = wr[c4], h = hv[c4];
            v += wq.x * h.x + wq.y * h.y + wq.z * h.z + wq.w * h.w;
        }
        Rls[t] = v;
    }
    __syncthreads();
    if (t < 64) {
        float pr = Rls[t], pi = Rls[64 + t];
        float nrm = fmaxf(sqrtf(pr * pr + pi * pi), 1e-12f);
        float* th = out + OUT_THETA + (size_t)row * 128 + t * 2;
        th[0] = pr / nrm;
        th[1] = pi / nrm;
    }
}

// ---------------- K4: einsums + MLPs + softmax + norm ----------------
__global__ __launch_bounds__(256) void k_tail(const float* __restrict__ Hre, const float* __restrict__ Him,
                                              const float* __restrict__ chre, const float* __restrict__ chim,
                                              const float* __restrict__ b1w, const float* __restrict__ b1b,
                                              const float* __restrict__ b2w, const float* __restrict__ b2b,
                                              const float* __restrict__ b3w, const float* __restrict__ b3b,
                                              const float* __restrict__ p1w, const float* __restrict__ p1b,
                                              const float* __restrict__ p2w, const float* __restrict__ p2b,
                                              float* __restrict__ out) {
    int b = blockIdx.x, t = threadIdx.x;
    __shared__ float trs[256], tis[256];
    __shared__ float red[512];
    __shared__ __align__(16) float cH[64];
    __shared__ __align__(16) float u1[128];
    __shared__ __align__(16) float u2[128];
    __shared__ __align__(16) float q1[128];
    __shared__ float wv[80];
    __shared__ float sc[4];

    const float* th = out + OUT_THETA + (size_t)b * 512;
    for (int i = t; i < 256; i += 256) { trs[i] = th[2 * i]; tis[i] = th[2 * i + 1]; }
    __syncthreads();

    {
        int part = t >> 5, km = t & 31, k = km >> 3, m = km & 7;
        const float* hr = Hre + (size_t)b * 8192 + m * 1024 + k;
        const float* hi = Him + (size_t)b * 8192 + m * 1024 + k;
        float a1 = 0.f, a2 = 0.f;
        for (int n = part * 8; n < part * 8 + 8; n++) {
#pragma unroll
            for (int l = 0; l < 4; l++) {
                float re = hr[n * 16 + l * 4], im = hi[n * 16 + l * 4];
                float tr = trs[l * 64 + n], ti = tis[l * 64 + n];
                a1 += re * tr + im * ti;
                a2 += re * ti - im * tr;
            }
        }
        red[(part * 32 + km) * 2 + 0] = a1;
        red[(part * 32 + km) * 2 + 1] = a2;
    }
    __syncthreads();
    if (t < 32) {
        float top = 0.f, bot = 0.f;
#pragma unroll
        for (int p = 0; p < 8; p++) { top += red[(p * 32 + t) * 2]; bot += red[(p * 32 + t) * 2 + 1]; }
        int k2 = t >> 3, m2 = t & 7;
        cH[k2 * 16 + m2]     = top + chre[b * 32 + t];
        cH[k2 * 16 + 8 + m2] = bot + chim[b * 32 + t];
    }
    __syncthreads();

    const float4* ch4 = reinterpret_cast<const float4*>(cH);
    if (t < 128) {
        float v = b1b[t];
        const float4* wq = reinterpret_cast<const float4*>(b1w + (size_t)t * 64);
#pragma unroll
        for (int j = 0; j < 16; j++) {
            float4 a = wq[j], c = ch4[j];
            v += a.x * c.x + a.y * c.y + a.z * c.z + a.w * c.w;
        }
        u1[t] = fmaxf(v, 0.f);
    } else {
        int o = t - 128;
        float v = p1b[o];
        const float4* wq = reinterpret_cast<const float4*>(p1w + (size_t)o * 64);
#pragma unroll
        for (int j = 0; j < 16; j++) {
            float4 a = wq[j], c = ch4[j];
            v += a.x * c.x + a.y * c.y + a.z * c.z + a.w * c.w;
        }
        q1[o] = fmaxf(v, 0.f);
    }
    __syncthreads();

    if (t < 128) {
        float v = b2b[t];
        const float4* wq = reinterpret_cast<const float4*>(b2w + (size_t)t * 128);
        const float4* uu = reinterpret_cast<const float4*>(u1);
#pragma unroll
        for (int j = 0; j < 32; j++) {
            float4 a = wq[j], c = uu[j];
            v += a.x * c.x + a.y * c.y + a.z * c.z + a.w * c.w;
        }
        u2[t] = fmaxf(v, 0.f);
    } else if (t < 130) {
        int o = t - 128;
        float v = p2b[o];
        const float4* wq = reinterpret_cast<const float4*>(p2w + (size_t)o * 128);
        const float4* qq = reinterpret_cast<const float4*>(q1);
#pragma unroll
        for (int j = 0; j < 32; j++) {
            float4 a = wq[j], c = qq[j];
            v += a.x * c.x + a.y * c.y + a.z * c.z + a.w * c.w;
        }
        sc[o] = v;
    }
    __syncthreads();

    if (t < 80) {
        float v = b3b[t];
        const float4* wq = reinterpret_cast<const float4*>(b3w + (size_t)t * 128);
        const float4* uu = reinterpret_cast<const float4*>(u2);
#pragma unroll
        for (int j = 0; j < 32; j++) {
            float4 a = wq[j], c = uu[j];
            v += a.x * c.x + a.y * c.y + a.z * c.z + a.w * c.w;
        }
        wv[t] = v;
    }
    __syncthreads();

    if (t == 0) {
        float mx = fmaxf(sc[0], sc[1]);
        float e0 = expf(sc[0] - mx), e1 = expf(sc[1] - mx);
        float s = e0 + e1;
        float mu0 = e0 / s, mu1 = e1 / s;
        out[OUT_MU + b * 2]     = mu0;
        out[OUT_MU + b * 2 + 1] = mu1;
        float ss = 0.f;
        for (int j = 0; j < 80; j++) ss += wv[j] * wv[j];
        float wn = fmaxf(sqrtf(ss), 1e-12f);
        sc[2] = 3.16227766017f * sqrtf(mu0) / wn;
    }
    __syncthreads();
    if (t < 80) out[b * 80 + t] = wv[t] * sc[2];
}

extern "C" void kernel_launch(void* const* d_in, const int* in_sizes, int n_in,
                              void* d_out, int out_size, void* d_ws, size_t ws_size,
                              hipStream_t stream) {
    const float* x    = (const float*)d_in[0];
    const float* Hre  = (const float*)d_in[1];
    const float* Him  = (const float*)d_in[2];
    const float* chre = (const float*)d_in[3];
    const float* chim = (const float*)d_in[4];
    const float* c1w  = (const float*)d_in[5];
    const float* c1b  = (const float*)d_in[6];
    const float* c2w  = (const float*)d_in[7];
    const float* c2b  = (const float*)d_in[8];
    const float* pl1w = (const float*)d_in[9];
    const float* pl1b = (const float*)d_in[10];
    const float* pl2w = (const float*)d_in[11];
    const float* pl2b = (const float*)d_in[12];
    const float* b1w  = (const float*)d_in[13];
    const float* b1b  = (const float*)d_in[14];
    const float* b2w  = (const float*)d_in[15];
    const float* b2b  = (const float*)d_in[16];
    const float* b3w  = (const float*)d_in[17];
    const float* b3b  = (const float*)d_in[18];
    const float* p1w  = (const float*)d_in[19];
    const float* p1b  = (const float*)d_in[20];
    const float* p2w  = (const float*)d_in[21];
    const float* p2b  = (const float*)d_in[22];
    float* out = (float*)d_out;

    char* ws = (char*)d_ws;
    // Ah/Al: 1024 local rows x FLATK ushorts = 68,157,440 B each (same footprint as before)
    unsigned short* Ah = (unsigned short*)(ws + 0);           //  68,157,440 B
    unsigned short* Al = (unsigned short*)(ws + 68157440u);   //  68,157,440 B
    float* P           = (float*)(ws + 136314880u);           //  33,554,432 B  (end 169,869,312)
    unsigned short* Bh = (unsigned short*)(ws + 169869312u);  //  17,039,360 B
    unsigned short* Bl = (unsigned short*)(ws + 186908672u);  //  17,039,360 B  (end 203,948,032; ws >= this, proven R7)
    // w2 fragment stash: last 16 KB of P = slice 15, rows 2040-2047. Written by k_cvtW
    // first; read by k_conv z0/z1. Only k_gemm z=1 writes P rows >= 1024 (stream-ordered
    // AFTER the last k_conv) -> safe.
    unsigned short* Wq = (unsigned short*)(ws + 169869312u - 16384u);

    k_cvtW<<<1, 256, 0, stream>>>(c2w, Wq);
    k_cvtB<<<8320, 256, 0, stream>>>((const float4*)pl1w, (ushort4*)Bh, (ushort4*)Bl, 2129920);
    for (int z = 0; z < 2; z++) {
        k_conv<<<dim3(1024, 9), 256, 0, stream>>>(x, c1w, c1b, Wq, c2b, Ah, Al, z);
        k_gemm<<<256, 512, 0, stream>>>(Ah, Al, Bh, Bl, P, z);
    }
    k_head<<<2048, 128, 0, stream>>>(P, pl1b, pl2w, pl2b, out);
    k_tail<<<512, 256, 0, stream>>>(Hre, Him, chre, chim, b1w, b1b, b2w, b2b,
                                    b3w, b3b, p1w, p1b, p2w, p2b, out);
}

// Round 8
// 470.844 us; speedup vs baseline: 1.1434x; 1.1434x over previous
//
#include <hip/hip_runtime.h>

#define ROWS 2048
#define FLATK 33280
#define SUBK 2080
#define NSTEP 65
#define S_DIM 520
#define SPLITP 16
#define OUT_THETA 40960
#define OUT_MU 303104
#define LOSCALE 2048.0f
#define INV_LOSCALE (1.0f/2048.0f)

typedef __attribute__((ext_vector_type(8))) _Float16 f16x8;
typedef __attribute__((ext_vector_type(8))) unsigned short u16x8;
typedef __attribute__((ext_vector_type(4))) float f32x4;

union H16 { _Float16 h; unsigned short u; };

static __device__ __forceinline__ void split16(float v, unsigned short& hi, unsigned short& lo) {
    H16 a, b;
    a.h = (_Float16)v;
    float r = (v - (float)a.h) * LOSCALE;
    b.h = (_Float16)r;
    hi = a.u; lo = b.u;
}

// async global->LDS, 16B per lane; lds base must be wave-uniform
static __device__ __forceinline__ void glds16(const unsigned short* g, unsigned short* l) {
    __builtin_amdgcn_global_load_lds((const __attribute__((address_space(1))) unsigned int*)g,
                                     (__attribute__((address_space(3))) unsigned int*)l,
                                     16, 0, 0);
}

// ---------------- K0: pl1_w fp32 -> f16 hi/lo planes ----------------
__global__ __launch_bounds__(256) void k_cvtB(const float4* __restrict__ in,
                                              ushort4* __restrict__ outh,
                                              ushort4* __restrict__ outl, int n4) {
    int i = blockIdx.x * 256 + threadIdx.x;
    if (i >= n4) return;
    float4 v = in[i];
    unsigned short h0, h1, h2, h3, l0, l1, l2, l3;
    split16(v.x, h0, l0); split16(v.y, h1, l1);
    split16(v.z, h2, l2); split16(v.w, h3, l3);
    outh[i] = make_ushort4(h0, h1, h2, h3);
    outl[i] = make_ushort4(l0, l1, l2, l3);
}

// ---------------- K0b: w2 fp32 -> pre-packed per-lane MFMA fragments hi/lo ----------------
__global__ __launch_bounds__(256) void k_cvtW(const float* __restrict__ w2,
                                              unsigned short* __restrict__ Wq) {
    int t = threadIdx.x;
    for (int s = t; s < 512; s += 256) {
        int otp = s >> 7, ks = (s >> 6) & 1, lane = s & 63;
        int m = lane & 15, kg = lane >> 4;
        const float* wp = w2 + (size_t)(otp * 16 + m) * 64 + ks * 32 + kg * 8;
#pragma unroll
        for (int j = 0; j < 8; j++) {
            unsigned short hh, ll;
            split16(wp[j], hh, ll);
            Wq[s * 8 + j] = hh;
            Wq[4096 + s * 8 + j] = ll;
        }
    }
}

// ---------------- K1: conv, R8 restructure: one block = one row x ALL 9 windows ----------------
// grid (1024), 256 thr (4 waves), z splits rows. Amortizes x/w1/w2-frag staging and
// launch overhead 9x (R7 counters: all-low latency-bound, ~3us overhead per ~1us work).
// x row staged ONCE into LDS [8][576] (zero-padded past 520 -> no bounds logic in loop).
// Per window: conv1 (wave w -> ch [16w,16w+16), pos=lane) -> h1 swizzled f16 hi/lo in
// LDS -> conv2 MFMA (4 ot-tiles) -> ushort4 stores. Inner code identical to R7.
__global__ __launch_bounds__(256) void k_conv(const float* __restrict__ x,
                                              const float* __restrict__ w1, const float* __restrict__ b1,
                                              const unsigned short* __restrict__ Wq,
                                              const float* __restrict__ b2,
                                              unsigned short* __restrict__ Ah, unsigned short* __restrict__ Al,
                                              int z) {
    __shared__ __align__(16) float xs[8 * 576];               // 18,432 B (pad 520..575 = 0)
    __shared__ __align__(16) float w1s[512];                  //  2 KB
    __shared__ float b1s[64];                                 // 256 B
    __shared__ __align__(16) unsigned short h1h[64 * 64];     //  8 KB
    __shared__ __align__(16) unsigned short h1l[64 * 64];     //  8 KB  -> ~37 KB, 4 blk/CU

    int t = threadIdx.x;
    int bll = blockIdx.x;                      // local row 0..1023
    int bl = z * 1024 + bll;                   // global (b,l) row
    int lane = t & 63, w = t >> 6;
    int m = lane & 15, kg = lane >> 4;

    // stage w1, b1 (once per block)
    for (int i = t; i < 512; i += 256) w1s[i] = w1[i];
    if (t < 64) b1s[t] = b1[t];

    // stage full x row as float4, zero pad (once per block)
    {
        const float4* xb4 = reinterpret_cast<const float4*>(x + (size_t)bl * (8 * S_DIM));
        for (int i = t; i < 1152; i += 256) {
            int ci = i / 144, p4 = i - ci * 144;
            float4 v = (p4 < 130) ? xb4[ci * 130 + p4] : make_float4(0.f, 0.f, 0.f, 0.f);
            *reinterpret_cast<float4*>(&xs[ci * 576 + p4 * 4]) = v;
        }
    }

    // w2 B-fragments for all 4 ot-tiles (pre-packed by k_cvtW) + b2 (once per block)
    f16x8 wh[4][2], wl[4][2];
    float b2v[4];
#pragma unroll
    for (int ot = 0; ot < 4; ot++) {
        b2v[ot] = b2[ot * 16 + m];
#pragma unroll
        for (int ks = 0; ks < 2; ks++) {
            int slot = (ot * 2 + ks) * 64 + lane;
            wh[ot][ks] = *(const f16x8*)&Wq[slot * 8];
            wl[ot][ks] = *(const f16x8*)&Wq[4096 + slot * 8];
        }
    }

    size_t Abase = (size_t)bll * FLATK;

    for (int st = 0; st < 9; st++) {
        __syncthreads();   // x/w staged (st=0); h1 fully consumed by all waves (st>0)
        int pbase = st * 64;

        // conv1: wave w -> channels [16w, 16w+16), pos = lane
        {
            int pos = lane;
            int cg0 = w * 16;
            float xv[8];
#pragma unroll
            for (int ci = 0; ci < 8; ci++) xv[ci] = xs[ci * 576 + pbase + pos];
#pragma unroll
            for (int half = 0; half < 2; half++) {
                u16x8 ph, pl;
#pragma unroll
                for (int j = 0; j < 8; j++) {
                    int c = cg0 + half * 8 + j;
                    const float4 wa = *(const float4*)&w1s[c * 8];
                    const float4 wb = *(const float4*)&w1s[c * 8 + 4];
                    float a = b1s[c]
                        + wa.x * xv[0] + wa.y * xv[1] + wa.z * xv[2] + wa.w * xv[3]
                        + wb.x * xv[4] + wb.y * xv[5] + wb.z * xv[6] + wb.w * xv[7];
                    a = fmaxf(a, 0.f);
                    unsigned short hh, ll;
                    split16(a, hh, ll);
                    ph[j] = hh; pl[j] = ll;
                }
                int g = (cg0 >> 3) + half;
                int off = pos * 64 + ((g ^ (pos & 7)) << 3);
                *(u16x8*)&h1h[off] = ph;
                *(u16x8*)&h1l[off] = pl;
            }
        }
        __syncthreads();

        // conv2 MFMA: wave w -> pos tile [w*16, w*16+16), all 64 outs (4 ot-tiles)
        int p0 = w * 16;
        int prow = p0 + m;
        f16x8 a_h[2], a_l[2];
#pragma unroll
        for (int ks = 0; ks < 2; ks++) {
            int g = ks * 4 + kg;
            int off = prow * 64 + ((g ^ (prow & 7)) << 3);
            a_h[ks] = *(const f16x8*)&h1h[off];
            a_l[ks] = *(const f16x8*)&h1l[off];
        }

        int pos4 = pbase + p0 + kg * 4;          // 4 consecutive positions per lane
        bool ok = pos4 < (S_DIM - 3);
#pragma unroll
        for (int ot = 0; ot < 4; ot++) {
            f32x4 ah = {0.f, 0.f, 0.f, 0.f}, am = {0.f, 0.f, 0.f, 0.f};
#pragma unroll
            for (int ks = 0; ks < 2; ks++) {
                ah = __builtin_amdgcn_mfma_f32_16x16x32_f16(a_h[ks], wh[ot][ks], ah, 0, 0, 0);
                am = __builtin_amdgcn_mfma_f32_16x16x32_f16(a_l[ks], wh[ot][ks], am, 0, 0, 0);
                am = __builtin_amdgcn_mfma_f32_16x16x32_f16(a_h[ks], wl[ot][ks], am, 0, 0, 0);
            }
            if (ok) {
                unsigned short hh[4], ll[4];
#pragma unroll
                for (int r = 0; r < 4; r++) {
                    float v = fmaxf(b2v[ot] + ah[r] + am[r] * INV_LOSCALE, 0.f);
                    split16(v, hh[r], ll[r]);
                }
                size_t off2 = Abase + (size_t)(ot * 16 + m) * S_DIM + pos4;
                *reinterpret_cast<ushort4*>(&Ah[off2]) = make_ushort4(hh[0], hh[1], hh[2], hh[3]);
                *reinterpret_cast<ushort4*>(&Al[off2]) = make_ushort4(ll[0], ll[1], ll[2], ll[3]);
            }
        }
    }
}

// ---------------- K2: MFMA GEMM, 64x256 tile over the z row-half, full-K slices ----------------
// (unchanged from R7)
__global__ __launch_bounds__(512) void k_gemm(const unsigned short* __restrict__ Ah,
                                              const unsigned short* __restrict__ Al,
                                              const unsigned short* __restrict__ Bh,
                                              const unsigned short* __restrict__ Bl,
                                              float* __restrict__ P, int z) {
    __shared__ __align__(16) unsigned short As_h[2][64 * 32];    // 2 x 4 KB
    __shared__ __align__(16) unsigned short As_l[2][64 * 32];    // 2 x 4 KB
    __shared__ __align__(16) unsigned short Bs_h[2][256 * 32];   // 2 x 16 KB
    __shared__ __align__(16) unsigned short Bs_l[2][256 * 32];   // 2 x 16 KB

    int t = threadIdx.x;
    int bid = blockIdx.x;
    int sk = bid & 15, rt = bid >> 4;
    int row0 = rt * 64;                       // local row within the z half
    int kb0 = sk * SUBK;

    int w = t >> 6, lane = t & 63;
    int srow = lane >> 2;                                   // 0..15
    int sg = ((lane & 3) ^ ((lane >> 3) & 3)) * 8;          // swizzled source granule

    const unsigned short* gA = (w < 4 ? Ah : Al)
        + (size_t)(row0 + (w & 3) * 16 + srow) * FLATK + kb0 + sg;
    const unsigned short* gBh0 = Bh + (size_t)(w * 32 + srow) * FLATK + kb0 + sg;
    const unsigned short* gBl0 = Bl + (size_t)(w * 32 + srow) * FLATK + kb0 + sg;
    const size_t strideB16 = (size_t)16 * FLATK;
    int aoff = ((w & 3) * 16) * 32;
    int boff0 = (w * 32) * 32;
    int boff1 = (w * 32 + 16) * 32;

    int m = lane & 15, kg = lane >> 4;
    int kgs = (kg ^ ((m >> 1) & 3)) * 8;                    // swizzled read granule

    f32x4 acc_h[4][2], acc_m[4][2];
#pragma unroll
    for (int i = 0; i < 4; i++)
#pragma unroll
        for (int j = 0; j < 2; j++) {
            acc_h[i][j] = (f32x4){0.f, 0.f, 0.f, 0.f};
            acc_m[i][j] = (f32x4){0.f, 0.f, 0.f, 0.f};
        }

#define STAGE(c) do {                                         \
        if (w < 4) glds16(gA, &As_h[c][aoff]);                \
        else       glds16(gA, &As_l[c][aoff]);                \
        glds16(gBh0, &Bs_h[c][boff0]);                        \
        glds16(gBh0 + strideB16, &Bs_h[c][boff1]);            \
        glds16(gBl0, &Bs_l[c][boff0]);                        \
        glds16(gBl0 + strideB16, &Bs_l[c][boff1]);            \
        gA += 32; gBh0 += 32; gBl0 += 32;                     \
    } while (0)

#define COMPUTE(c) do {                                                                   \
        f16x8 a_h[4], a_l[4], b_h[2], b_l[2];                                             \
        _Pragma("unroll")                                                                 \
        for (int i = 0; i < 4; i++) {                                                     \
            int off = (i * 16 + m) * 32 + kgs;                                            \
            a_h[i] = *reinterpret_cast<const f16x8*>(&As_h[c][off]);                      \
            a_l[i] = *reinterpret_cast<const f16x8*>(&As_l[c][off]);                      \
        }                                                                                 \
        _Pragma("unroll")                                                                 \
        for (int j = 0; j < 2; j++) {                                                     \
            int off = (w * 32 + j * 16 + m) * 32 + kgs;                                   \
            b_h[j] = *reinterpret_cast<const f16x8*>(&Bs_h[c][off]);                      \
            b_l[j] = *reinterpret_cast<const f16x8*>(&Bs_l[c][off]);                      \
        }                                                                                 \
        _Pragma("unroll")                                                                 \
        for (int i = 0; i < 4; i++)                                                       \
            _Pragma("unroll")                                                             \
            for (int j = 0; j < 2; j++) {                                                 \
                acc_h[i][j] = __builtin_amdgcn_mfma_f32_16x16x32_f16(a_h[i], b_h[j], acc_h[i][j], 0, 0, 0); \
                acc_m[i][j] = __builtin_amdgcn_mfma_f32_16x16x32_f16(a_l[i], b_h[j], acc_m[i][j], 0, 0, 0); \
                acc_m[i][j] = __builtin_amdgcn_mfma_f32_16x16x32_f16(a_h[i], b_l[j], acc_m[i][j], 0, 0, 0); \
            }                                                                             \
    } while (0)

    STAGE(0);
    __syncthreads();

    int cur = 0;
    for (int it = 0; it < NSTEP - 1; ++it) {
        STAGE(cur ^ 1);
        COMPUTE(cur);
        __syncthreads();
        cur ^= 1;
    }
    COMPUTE(cur);

#undef STAGE
#undef COMPUTE

    float* Pp = P + (size_t)sk * (ROWS * 256);
    int rbase = z * 1024 + row0 + kg * 4;
    int cbase = w * 32 + m;
#pragma unroll
    for (int i = 0; i < 4; i++)
#pragma unroll
        for (int j = 0; j < 2; j++)
#pragma unroll
            for (int r = 0; r < 4; r++) {
                int rr = rbase + i * 16 + r;
                int cc = cbase + j * 16;
                Pp[(size_t)rr * 256 + cc] = acc_h[i][j][r] + acc_m[i][j][r] * INV_LOSCALE;
            }
}

// ---------------- K3: reduce + bias + relu + pl2 + Theta ----------------
__global__ __launch_bounds__(128) void k_head(const float* __restrict__ P,
                                              const float* __restrict__ pl1b,
                                              const float* __restrict__ pl2w,
                                              const float* __restrict__ pl2b,
                                              float* __restrict__ out) {
    __shared__ __align__(16) float hs[256];
    __shared__ float Rls[128];
    int row = blockIdx.x;
    int t = threadIdx.x;
    for (int c = t; c < 256; c += 128) {
        float v = pl1b[c];
#pragma unroll
        for (int zz = 0; zz < SPLITP; zz++) v += P[(size_t)zz * (ROWS * 256) + (size_t)row * 256 + c];
        hs[c] = fmaxf(v, 0.f);
    }
    __syncthreads();
    {
        float v = pl2b[t];
        const float4* wr = reinterpret_cast<const float4*>(pl2w + (size_t)t * 256);
        const float4* hv = reinterpret_cast<const float4*>(hs);
#pragma unroll 8
        for (int c4 = 0; c4 < 64; c4++) {
            float4 wq = wr[c4], h = hv[c4];
            v += wq.x * h.x + wq.y * h.y + wq.z * h.z + wq.w * h.w;
        }
        Rls[t] = v;
    }
    __syncthreads();
    if (t < 64) {
        float pr = Rls[t], pi = Rls[64 + t];
        float nrm = fmaxf(sqrtf(pr * pr + pi * pi), 1e-12f);
        float* th = out + OUT_THETA + (size_t)row * 128 + t * 2;
        th[0] = pr / nrm;
        th[1] = pi / nrm;
    }
}

// ---------------- K4: einsums + MLPs + softmax + norm ----------------
__global__ __launch_bounds__(256) void k_tail(const float* __restrict__ Hre, const float* __restrict__ Him,
                                              const float* __restrict__ chre, const float* __restrict__ chim,
                                              const float* __restrict__ b1w, const float* __restrict__ b1b,
                                              const float* __restrict__ b2w, const float* __restrict__ b2b,
                                              const float* __restrict__ b3w, const float* __restrict__ b3b,
                                              const float* __restrict__ p1w, const float* __restrict__ p1b,
                                              const float* __restrict__ p2w, const float* __restrict__ p2b,
                                              float* __restrict__ out) {
    int b = blockIdx.x, t = threadIdx.x;
    __shared__ float trs[256], tis[256];
    __shared__ float red[512];
    __shared__ __align__(16) float cH[64];
    __shared__ __align__(16) float u1[128];
    __shared__ __align__(16) float u2[128];
    __shared__ __align__(16) float q1[128];
    __shared__ float wv[80];
    __shared__ float sc[4];

    const float* th = out + OUT_THETA + (size_t)b * 512;
    for (int i = t; i < 256; i += 256) { trs[i] = th[2 * i]; tis[i] = th[2 * i + 1]; }
    __syncthreads();

    {
        int part = t >> 5, km = t & 31, k = km >> 3, m = km & 7;
        const float* hr = Hre + (size_t)b * 8192 + m * 1024 + k;
        const float* hi = Him + (size_t)b * 8192 + m * 1024 + k;
        float a1 = 0.f, a2 = 0.f;
        for (int n = part * 8; n < part * 8 + 8; n++) {
#pragma unroll
            for (int l = 0; l < 4; l++) {
                float re = hr[n * 16 + l * 4], im = hi[n * 16 + l * 4];
                float tr = trs[l * 64 + n], ti = tis[l * 64 + n];
                a1 += re * tr + im * ti;
                a2 += re * ti - im * tr;
            }
        }
        red[(part * 32 + km) * 2 + 0] = a1;
        red[(part * 32 + km) * 2 + 1] = a2;
    }
    __syncthreads();
    if (t < 32) {
        float top = 0.f, bot = 0.f;
#pragma unroll
        for (int p = 0; p < 8; p++) { top += red[(p * 32 + t) * 2]; bot += red[(p * 32 + t) * 2 + 1]; }
        int k2 = t >> 3, m2 = t & 7;
        cH[k2 * 16 + m2]     = top + chre[b * 32 + t];
        cH[k2 * 16 + 8 + m2] = bot + chim[b * 32 + t];
    }
    __syncthreads();

    const float4* ch4 = reinterpret_cast<const float4*>(cH);
    if (t < 128) {
        float v = b1b[t];
        const float4* wq = reinterpret_cast<const float4*>(b1w + (size_t)t * 64);
#pragma unroll
        for (int j = 0; j < 16; j++) {
            float4 a = wq[j], c = ch4[j];
            v += a.x * c.x + a.y * c.y + a.z * c.z + a.w * c.w;
        }
        u1[t] = fmaxf(v, 0.f);
    } else {
        int o = t - 128;
        float v = p1b[o];
        const float4* wq = reinterpret_cast<const float4*>(p1w + (size_t)o * 64);
#pragma unroll
        for (int j = 0; j < 16; j++) {
            float4 a = wq[j], c = ch4[j];
            v += a.x * c.x + a.y * c.y + a.z * c.z + a.w * c.w;
        }
        q1[o] = fmaxf(v, 0.f);
    }
    __syncthreads();

    if (t < 128) {
        float v = b2b[t];
        const float4* wq = reinterpret_cast<const float4*>(b2w + (size_t)t * 128);
        const float4* uu = reinterpret_cast<const float4*>(u1);
#pragma unroll
        for (int j = 0; j < 32; j++) {
            float4 a = wq[j], c = uu[j];
            v += a.x * c.x + a.y * c.y + a.z * c.z + a.w * c.w;
        }
        u2[t] = fmaxf(v, 0.f);
    } else if (t < 130) {
        int o = t - 128;
        float v = p2b[o];
        const float4* wq = reinterpret_cast<const float4*>(p2w + (size_t)o * 128);
        const float4* qq = reinterpret_cast<const float4*>(q1);
#pragma unroll
        for (int j = 0; j < 32; j++) {
            float4 a = wq[j], c = qq[j];
            v += a.x * c.x + a.y * c.y + a.z * c.z + a.w * c.w;
        }
        sc[o] = v;
    }
    __syncthreads();

    if (t < 80) {
        float v = b3b[t];
        const float4* wq = reinterpret_cast<const float4*>(b3w + (size_t)t * 128);
        const float4* uu = reinterpret_cast<const float4*>(u2);
#pragma unroll
        for (int j = 0; j < 32; j++) {
            float4 a = wq[j], c = uu[j];
            v += a.x * c.x + a.y * c.y + a.z * c.z + a.w * c.w;
        }
        wv[t] = v;
    }
    __syncthreads();

    if (t == 0) {
        float mx = fmaxf(sc[0], sc[1]);
        float e0 = expf(sc[0] - mx), e1 = expf(sc[1] - mx);
        float s = e0 + e1;
        float mu0 = e0 / s, mu1 = e1 / s;
        out[OUT_MU + b * 2]     = mu0;
        out[OUT_MU + b * 2 + 1] = mu1;
        float ss = 0.f;
        for (int j = 0; j < 80; j++) ss += wv[j] * wv[j];
        float wn = fmaxf(sqrtf(ss), 1e-12f);
        sc[2] = 3.16227766017f * sqrtf(mu0) / wn;
    }
    __syncthreads();
    if (t < 80) out[b * 80 + t] = wv[t] * sc[2];
}

extern "C" void kernel_launch(void* const* d_in, const int* in_sizes, int n_in,
                              void* d_out, int out_size, void* d_ws, size_t ws_size,
                              hipStream_t stream) {
    const float* x    = (const float*)d_in[0];
    const float* Hre  = (const float*)d_in[1];
    const float* Him  = (const float*)d_in[2];
    const float* chre = (const float*)d_in[3];
    const float* chim = (const float*)d_in[4];
    const float* c1w  = (const float*)d_in[5];
    const float* c1b  = (const float*)d_in[6];
    const float* c2w  = (const float*)d_in[7];
    const float* c2b  = (const float*)d_in[8];
    const float* pl1w = (const float*)d_in[9];
    const float* pl1b = (const float*)d_in[10];
    const float* pl2w = (const float*)d_in[11];
    const float* pl2b = (const float*)d_in[12];
    const float* b1w  = (const float*)d_in[13];
    const float* b1b  = (const float*)d_in[14];
    const float* b2w  = (const float*)d_in[15];
    const float* b2b  = (const float*)d_in[16];
    const float* b3w  = (const float*)d_in[17];
    const float* b3b  = (const float*)d_in[18];
    const float* p1w  = (const float*)d_in[19];
    const float* p1b  = (const float*)d_in[20];
    const float* p2w  = (const float*)d_in[21];
    const float* p2b  = (const float*)d_in[22];
    float* out = (float*)d_out;

    char* ws = (char*)d_ws;
    // Ah/Al: 1024 local rows x FLATK ushorts = 68,157,440 B each
    unsigned short* Ah = (unsigned short*)(ws + 0);           //  68,157,440 B
    unsigned short* Al = (unsigned short*)(ws + 68157440u);   //  68,157,440 B
    float* P           = (float*)(ws + 136314880u);           //  33,554,432 B  (end 169,869,312)
    unsigned short* Bh = (unsigned short*)(ws + 169869312u);  //  17,039,360 B
    unsigned short* Bl = (unsigned short*)(ws + 186908672u);  //  17,039,360 B  (end 203,948,032)
    // w2 fragment stash: last 16 KB of P = slice 15, rows 2040-2047. Written by k_cvtW
    // first; read by k_conv z0/z1. Only k_gemm z=1 writes P rows >= 1024 (stream-ordered
    // AFTER the last k_conv) -> safe.
    unsigned short* Wq = (unsigned short*)(ws + 169869312u - 16384u);

    k_cvtW<<<1, 256, 0, stream>>>(c2w, Wq);
    k_cvtB<<<8320, 256, 0, stream>>>((const float4*)pl1w, (ushort4*)Bh, (ushort4*)Bl, 2129920);
    for (int z = 0; z < 2; z++) {
        k_conv<<<1024, 256, 0, stream>>>(x, c1w, c1b, Wq, c2b, Ah, Al, z);
        k_gemm<<<256, 512, 0, stream>>>(Ah, Al, Bh, Bl, P, z);
    }
    k_head<<<2048, 128, 0, stream>>>(P, pl1b, pl2w, pl2b, out);
    k_tail<<<512, 256, 0, stream>>>(Hre, Him, chre, chim, b1w, b1b, b2w, b2b,
                                    b3w, b3b, p1w, p1b, p2w, p2b, out);
}